// Round 2
// baseline (259.339 us; speedup 1.0000x reference)
//
#include <hip/hip_runtime.h>

// Problem constants (from reference)
#define KLEN 64
#define CHUNK_L 128
#define WARMUP 256
#define ROUTE_SHAPE 2.5f
#define S1_INIT_V 50.0f
#define S2_INIT_V 250.0f

// Workspace float offsets
#define WS_PHYS 0     // 32 floats (29 used)
#define WS_KERN 32    // 64 floats
#define WS_DYN  96    // s1s[nchunk], q12s[nchunk], s2s[nchunk], runoff[T]

__constant__ float c_LOW[29] = {
    50.0f, 100.0f, 0.05f, 0.05f, 0.05f, 0.05f, 0.01f, 1.0f, 1.0f, 1.0f,
    0.05f, 0.01f, 0.001f, 1.0f, 0.001f, 0.001f, 0.001f, 0.05f, 0.001f, 5.0f,
    2.0f, 0.01f, -2.0f, -2.0f, 1.0f, -9.8f, 0.0f, 1.0f, 0.0f};
__constant__ float c_HIGH[29] = {
    5000.0f, 10000.0f, 0.95f, 0.95f, 0.95f, 0.95f, 1000.0f, 20.0f, 250.0f, 5.0f,
    0.95f, 1000.0f, 10000.0f, 10.0f, 0.25f, 0.25f, 0.25f, 0.95f, 3.0f, 10.0f,
    5.0f, 5.0f, 4.0f, 4.0f, 10.0f, 0.0f, 1.0f, 10.0f, 10.0f};

__device__ __forceinline__ float fpow(float x, float e) {
    // x >= 0 guaranteed by callers; x==0 -> log2=-inf -> exp2=0 (correct for e>0)
    return exp2f(e * __log2f(x));
}
__device__ __forceinline__ float clamp01(float x) { return fminf(fmaxf(x, 0.0f), 1.0f); }

// ---- Phase 0: physical params + routing kernel (1 wave) ----
__global__ void k_params(const float* __restrict__ raw, float* __restrict__ ws) {
    int t = threadIdx.x;  // 0..63
    __shared__ float sphys[29];
    if (t < 29) {
        float s = 1.0f / (1.0f + __expf(-raw[t]));
        float p = c_LOW[t] + (c_HIGH[t] - c_LOW[t]) * s;
        sphys[t] = p;
        ws[WS_PHYS + t] = p;
    }
    __syncthreads();
    float delay = sphys[21];  // mu_t
    float theta = fmaxf(delay, 1e-3f) * (1.0f / ROUTE_SHAPE);
    float tt = (float)t + 0.5f;
    float logk = (ROUTE_SHAPE - 1.0f) * __logf(tt) - tt / theta;
    float m = logk;
#pragma unroll
    for (int o = 32; o >= 1; o >>= 1) m = fmaxf(m, __shfl_xor(m, o, 64));
    float e = __expf(logk - m);
    float s = e;
#pragma unroll
    for (int o = 32; o >= 1; o >>= 1) s += __shfl_xor(s, o, 64);
    ws[WS_KERN + t] = e / s;
}

// ---- Phase 1: S1 spin-up per chunk; outputs exact chunk-start S1 + chunk sum of q12 ----
__global__ void k_s1(const float* __restrict__ forc, const float* __restrict__ ws,
                     float* __restrict__ s1s, float* __restrict__ q12s,
                     int T, int nchunk) {
    int j = blockIdx.x * blockDim.x + threadIdx.x;
    if (j >= nchunk) return;
    const float S1max = ws[WS_PHYS + 0];
    const float f_tens = ws[WS_PHYS + 2];
    const float ku = ws[WS_PHYS + 6];
    const float cc = ws[WS_PHYS + 7];
    const float ki = ws[WS_PHYS + 11];
    const float b = ws[WS_PHYS + 18];
    const float Train = ws[WS_PHYS + 22];
    const float invS1 = 1.0f / S1max, invft = 1.0f / f_tens;

    int t0 = j * CHUNK_L;
    int tend = min(t0 + CHUNK_L, T);
    int ts = t0 - WARMUP;
    if (ts < 0) ts = 0;

    float S1 = S1_INIT_V;
    for (int t = ts; t < t0; ++t) {  // warm-up: contraction ~0.8/step erases init
        float prcp = forc[3 * t], pet = forc[3 * t + 1], temp = forc[3 * t + 2];
        float rain = temp > Train ? prcp : 0.0f;
        float s1f = clamp01(S1 * invS1);
        float e1 = pet * fminf(s1f * invft, 1.0f);
        float qsx = rain * fpow(s1f, b);
        float q12 = ku * fpow(s1f, cc);
        float qif = ki * s1f;
        S1 = fminf(fmaxf(S1 + rain - qsx - e1 - q12 - qif, 0.0f), S1max);
    }
    s1s[j] = S1;  // exact chunk-start state (to fp32 roundoff)
    float Q = 0.0f;
    for (int t = t0; t < tend; ++t) {
        float prcp = forc[3 * t], pet = forc[3 * t + 1], temp = forc[3 * t + 2];
        float rain = temp > Train ? prcp : 0.0f;
        float s1f = clamp01(S1 * invS1);
        float e1 = pet * fminf(s1f * invft, 1.0f);
        float qsx = rain * fpow(s1f, b);
        float q12 = ku * fpow(s1f, cc);
        float qif = ki * s1f;
        S1 = fminf(fmaxf(S1 + rain - qsx - e1 - q12 - qif, 0.0f), S1max);
        Q += q12;
    }
    q12s[j] = Q;
}

// ---- Phase 2: coarse S2 chunk-level scan (sequential; S2 map is near-identity) ----
__global__ void k_s2coarse(const float* __restrict__ ws, const float* __restrict__ q12s,
                           float* __restrict__ s2s, int nchunk) {
    if (threadIdx.x != 0 || blockIdx.x != 0) return;
    const float S2max = ws[WS_PHYS + 1];
    const float ks = ws[WS_PHYS + 12];
    const float nn = ws[WS_PHYS + 13];
    const float invS2 = 1.0f / S2max;
    float S2 = S2_INIT_V;
    for (int j = 0; j < nchunk; ++j) {
        s2s[j] = S2;
        float s2f = clamp01(S2 * invS2);
        float qb = ks * fpow(s2f, nn);
        S2 = fminf(fmaxf(S2 + q12s[j] - (float)CHUNK_L * qb, 0.0f), S2max);
    }
}

// ---- Phase 3: exact per-chunk re-simulation of (S1,S2), write runoff ----
__global__ void k_sim(const float* __restrict__ forc, const float* __restrict__ ws,
                      const float* __restrict__ s1s, const float* __restrict__ s2s,
                      float* __restrict__ runoff, int T, int nchunk) {
    int j = blockIdx.x * blockDim.x + threadIdx.x;
    if (j >= nchunk) return;
    const float S1max = ws[WS_PHYS + 0];
    const float S2max = ws[WS_PHYS + 1];
    const float f_tens = ws[WS_PHYS + 2];
    const float ku = ws[WS_PHYS + 6];
    const float cc = ws[WS_PHYS + 7];
    const float ki = ws[WS_PHYS + 11];
    const float ks = ws[WS_PHYS + 12];
    const float nn = ws[WS_PHYS + 13];
    const float b = ws[WS_PHYS + 18];
    const float Train = ws[WS_PHYS + 22];
    const float invS1 = 1.0f / S1max, invS2 = 1.0f / S2max, invft = 1.0f / f_tens;

    int t0 = j * CHUNK_L;
    int tend = min(t0 + CHUNK_L, T);
    float S1 = s1s[j];
    float S2 = s2s[j];
    for (int t = t0; t < tend; ++t) {
        float prcp = forc[3 * t], pet = forc[3 * t + 1], temp = forc[3 * t + 2];
        float rain = temp > Train ? prcp : 0.0f;
        float s1f = clamp01(S1 * invS1);
        float s2f = clamp01(S2 * invS2);
        float e1 = pet * fminf(s1f * invft, 1.0f);
        float qsx = rain * fpow(s1f, b);
        float q12 = ku * fpow(s1f, cc);
        float qif = ki * s1f;
        float qb = ks * fpow(s2f, nn);
        runoff[t] = qsx + qif + qb;
        S1 = fminf(fmaxf(S1 + rain - qsx - e1 - q12 - qif, 0.0f), S1max);
        S2 = fminf(fmaxf(S2 + q12 - qb, 0.0f), S2max);
    }
}

// ---- Phase 4: causal gamma-kernel routing conv (LDS-staged) ----
__global__ void k_route(const float* __restrict__ runoff, const float* __restrict__ ws,
                        float* __restrict__ out, int T) {
    __shared__ float ls[256 + KLEN - 1];
    __shared__ float ker[KLEN];
    int tid = threadIdx.x;
    int base = blockIdx.x * 256;
    if (tid < KLEN) ker[tid] = ws[WS_KERN + tid];
    for (int i = tid; i < 256 + KLEN - 1; i += 256) {
        int t = base - (KLEN - 1) + i;
        ls[i] = (t >= 0 && t < T) ? runoff[t] : 0.0f;
    }
    __syncthreads();
    float acc = 0.0f;
#pragma unroll
    for (int k = 0; k < KLEN; ++k) acc += ker[k] * ls[tid + (KLEN - 1) - k];
    int t = base + tid;
    if (t < T) out[t] = acc;
}

extern "C" void kernel_launch(void* const* d_in, const int* in_sizes, int n_in,
                              void* d_out, int out_size, void* d_ws, size_t ws_size,
                              hipStream_t stream) {
    const float* forcing = (const float*)d_in[0];  // [T,3]
    const float* raw = (const float*)d_in[1];      // [29]
    float* out = (float*)d_out;
    float* ws = (float*)d_ws;

    int T = in_sizes[0] / 3;
    int nchunk = (T + CHUNK_L - 1) / CHUNK_L;

    float* s1s = ws + WS_DYN;
    float* q12s = s1s + nchunk;
    float* s2s = q12s + nchunk;
    float* runoff = s2s + nchunk;

    k_params<<<1, 64, 0, stream>>>(raw, ws);
    k_s1<<<(nchunk + 255) / 256, 256, 0, stream>>>(forcing, ws, s1s, q12s, T, nchunk);
    k_s2coarse<<<1, 64, 0, stream>>>(ws, q12s, s2s, nchunk);
    k_sim<<<(nchunk + 255) / 256, 256, 0, stream>>>(forcing, ws, s1s, s2s, runoff, T, nchunk);
    k_route<<<(T + 255) / 256, 256, 0, stream>>>(runoff, ws, out, T);
}

// Round 3
// 136.883 us; speedup vs baseline: 1.8946x; 1.8946x over previous
//
#include <hip/hip_runtime.h>

#define KLEN 64
#define CHUNK_L 128
#define WARMUP 128          // contraction ~0.8/step -> 0.8^128 ~ 4e-13 relative
#define S1_INIT_V 50.0f
#define S2_INIT_V 250.0f

__device__ __forceinline__ float fpow(float x, float e) {
    // x >= 0; x==0 -> log2=-inf -> exp2=0 (correct, exponents here are >0)
    return exp2f(e * __log2f(x));
}
__device__ __forceinline__ float clamp01(float x) { return fminf(fmaxf(x, 0.0f), 1.0f); }
__device__ __forceinline__ float physp(const float* raw, int i, float lo, float hi) {
    return lo + (hi - lo) / (1.0f + __expf(-raw[i]));
}

// ---- 8-step forcing group: 24 floats = 6 float4 (16B-aligned when t%8==0) ----
struct F8 { float4 v[6]; };
__device__ __forceinline__ F8 load_f8(const float* __restrict__ forc, int t) {
    const float4* p = (const float4*)(forc + 3 * t);
    F8 r;
#pragma unroll
    for (int k = 0; k < 6; ++k) r.v[k] = p[k];
    return r;
}
__device__ __forceinline__ float f4c(const float4& v, int c) {
    return c == 0 ? v.x : c == 1 ? v.y : c == 2 ? v.z : v.w;
}
__device__ __forceinline__ float f8_get(const F8& f, int i) { return f4c(f.v[i >> 2], i & 3); }

// ---- Phase 1: S1 spin-up per chunk -> exact chunk-start S1 + chunk-sum of q12 ----
__global__ void k_s1(const float* __restrict__ forc, const float* __restrict__ raw,
                     float* __restrict__ s1s, float* __restrict__ q12s,
                     int T, int nchunk) {
    int j = blockIdx.x * blockDim.x + threadIdx.x;
    if (j >= nchunk) return;
    const float S1max  = physp(raw, 0, 50.0f, 5000.0f);
    const float f_tens = physp(raw, 2, 0.05f, 0.95f);
    const float ku     = physp(raw, 6, 0.01f, 1000.0f);
    const float cc     = physp(raw, 7, 1.0f, 20.0f);
    const float ki     = physp(raw, 11, 0.01f, 1000.0f);
    const float b      = physp(raw, 18, 0.001f, 3.0f);
    const float Train  = physp(raw, 22, -2.0f, 4.0f);
    const float invS1 = 1.0f / S1max, invft = 1.0f / f_tens;

    int t0 = j * CHUNK_L;
    int tend = min(t0 + CHUNK_L, T);
    int ts = max(t0 - WARMUP, 0);

    float S1 = S1_INIT_V;

#define S1_CORE(pr, pe, te, QACC)                                         \
    {                                                                     \
        float rain = (te) > Train ? (pr) : 0.0f;                          \
        float s1f = clamp01(S1 * invS1);                                  \
        float e1 = (pe)*fminf(s1f * invft, 1.0f);                         \
        float qsx = rain * fpow(s1f, b);                                  \
        float q12 = ku * fpow(s1f, cc);                                   \
        float qif = ki * s1f;                                             \
        S1 = fminf(fmaxf(S1 + rain - qsx - e1 - q12 - qif, 0.0f), S1max); \
        QACC;                                                             \
    }

    // warm-up ((t0-ts) is a multiple of 8; groups of 8 with 1-ahead prefetch)
    int ngw = (t0 - ts) >> 3;
    F8 cur = load_f8(forc, ts);
    for (int g = 0; g < ngw; ++g) {
        F8 nxt = load_f8(forc, ts + 8 * (g + 1));  // last warm-up prefetch = first main group
#pragma unroll
        for (int s = 0; s < 8; ++s) {
            float pr = f8_get(cur, 3 * s), pe = f8_get(cur, 3 * s + 1), te = f8_get(cur, 3 * s + 2);
            S1_CORE(pr, pe, te, );
        }
        cur = nxt;
    }
    s1s[j] = S1;

    float Q = 0.0f;
    int ngm = (tend - t0) >> 3;
    for (int g = 0; g < ngm; ++g) {
        F8 nxt = load_f8(forc, t0 + 8 * min(g + 1, ngm - 1));
#pragma unroll
        for (int s = 0; s < 8; ++s) {
            float pr = f8_get(cur, 3 * s), pe = f8_get(cur, 3 * s + 1), te = f8_get(cur, 3 * s + 2);
            S1_CORE(pr, pe, te, Q += q12);
        }
        cur = nxt;
    }
    for (int t = t0 + 8 * ngm; t < tend; ++t) {  // generic tail
        float pr = forc[3 * t], pe = forc[3 * t + 1], te = forc[3 * t + 2];
        S1_CORE(pr, pe, te, Q += q12);
    }
    q12s[j] = Q;
}

// ---- Phase 2: coarse S2 scan, qb frozen per 8-chunk window (err ~1e-6 in qb) ----
__global__ void k_s2coarse(const float* __restrict__ raw, const float* __restrict__ q12s,
                           float* __restrict__ s2s, int nchunk) {
    if (threadIdx.x != 0 || blockIdx.x != 0) return;
    const float S2max = physp(raw, 1, 100.0f, 10000.0f);
    const float ks    = physp(raw, 12, 0.001f, 10000.0f);
    const float nn    = physp(raw, 13, 1.0f, 10.0f);
    const float invS2 = 1.0f / S2max;

    float S2 = S2_INIT_V;
    int nwin = nchunk >> 3;
    const float4* q4 = (const float4*)q12s;
    float4 qa = q4[0], qb4 = q4[1];
    for (int w = 0; w < nwin; ++w) {
        float4 na = q4[min(2 * w + 2, 2 * nwin - 2)];
        float4 nb = q4[min(2 * w + 3, 2 * nwin - 1)];
        float s2f = clamp01(S2 * invS2);
        float d = (float)CHUNK_L * ks * fpow(s2f, nn);
        float s[8];
        s[0] = S2; S2 = fminf(fmaxf(S2 + qa.x - d, 0.0f), S2max);
        s[1] = S2; S2 = fminf(fmaxf(S2 + qa.y - d, 0.0f), S2max);
        s[2] = S2; S2 = fminf(fmaxf(S2 + qa.z - d, 0.0f), S2max);
        s[3] = S2; S2 = fminf(fmaxf(S2 + qa.w - d, 0.0f), S2max);
        s[4] = S2; S2 = fminf(fmaxf(S2 + qb4.x - d, 0.0f), S2max);
        s[5] = S2; S2 = fminf(fmaxf(S2 + qb4.y - d, 0.0f), S2max);
        s[6] = S2; S2 = fminf(fmaxf(S2 + qb4.z - d, 0.0f), S2max);
        s[7] = S2; S2 = fminf(fmaxf(S2 + qb4.w - d, 0.0f), S2max);
        float4* sp = (float4*)(s2s + 8 * w);
        sp[0] = make_float4(s[0], s[1], s[2], s[3]);
        sp[1] = make_float4(s[4], s[5], s[6], s[7]);
        qa = na; qb4 = nb;
    }
    for (int j = 8 * nwin; j < nchunk; ++j) {  // generic tail
        s2s[j] = S2;
        float s2f = clamp01(S2 * invS2);
        float qb = ks * fpow(s2f, nn);
        S2 = fminf(fmaxf(S2 + q12s[j] - (float)CHUNK_L * qb, 0.0f), S2max);
    }
}

// ---- Phase 3: exact per-chunk re-simulation, writes runoff ----
__global__ void k_sim(const float* __restrict__ forc, const float* __restrict__ raw,
                      const float* __restrict__ s1s, const float* __restrict__ s2s,
                      float* __restrict__ runoff, int T, int nchunk) {
    int j = blockIdx.x * blockDim.x + threadIdx.x;
    if (j >= nchunk) return;
    const float S1max  = physp(raw, 0, 50.0f, 5000.0f);
    const float S2max  = physp(raw, 1, 100.0f, 10000.0f);
    const float f_tens = physp(raw, 2, 0.05f, 0.95f);
    const float ku     = physp(raw, 6, 0.01f, 1000.0f);
    const float cc     = physp(raw, 7, 1.0f, 20.0f);
    const float ki     = physp(raw, 11, 0.01f, 1000.0f);
    const float ks     = physp(raw, 12, 0.001f, 10000.0f);
    const float nn     = physp(raw, 13, 1.0f, 10.0f);
    const float b      = physp(raw, 18, 0.001f, 3.0f);
    const float Train  = physp(raw, 22, -2.0f, 4.0f);
    const float invS1 = 1.0f / S1max, invS2 = 1.0f / S2max, invft = 1.0f / f_tens;

    int t0 = j * CHUNK_L;
    int tend = min(t0 + CHUNK_L, T);
    float S1 = s1s[j];
    float S2 = s2s[j];

#define SIM_CORE(pr, pe, te, EMIT)                                        \
    {                                                                     \
        float rain = (te) > Train ? (pr) : 0.0f;                          \
        float s1f = clamp01(S1 * invS1);                                  \
        float s2f = clamp01(S2 * invS2);                                  \
        float e1 = (pe)*fminf(s1f * invft, 1.0f);                         \
        float qsx = rain * fpow(s1f, b);                                  \
        float q12 = ku * fpow(s1f, cc);                                   \
        float qif = ki * s1f;                                             \
        float qb = ks * fpow(s2f, nn);                                    \
        EMIT;                                                             \
        S1 = fminf(fmaxf(S1 + rain - qsx - e1 - q12 - qif, 0.0f), S1max); \
        S2 = fminf(fmaxf(S2 + q12 - qb, 0.0f), S2max);                    \
    }

    int ngm = (tend - t0) >> 3;
    F8 cur = load_f8(forc, t0);
    for (int g = 0; g < ngm; ++g) {
        F8 nxt = load_f8(forc, t0 + 8 * min(g + 1, ngm - 1));
        float ro[8];
#pragma unroll
        for (int s = 0; s < 8; ++s) {
            float pr = f8_get(cur, 3 * s), pe = f8_get(cur, 3 * s + 1), te = f8_get(cur, 3 * s + 2);
            SIM_CORE(pr, pe, te, ro[s] = qsx + qif + qb);
        }
        float4* rp = (float4*)(runoff + t0 + 8 * g);
        rp[0] = make_float4(ro[0], ro[1], ro[2], ro[3]);
        rp[1] = make_float4(ro[4], ro[5], ro[6], ro[7]);
        cur = nxt;
    }
    for (int t = t0 + 8 * ngm; t < tend; ++t) {  // generic tail
        float pr = forc[3 * t], pe = forc[3 * t + 1], te = forc[3 * t + 2];
        SIM_CORE(pr, pe, te, runoff[t] = qsx + qif + qb);
    }
}

// ---- Phase 4: causal gamma-kernel routing conv (self-computes weights) ----
__global__ void k_route(const float* __restrict__ runoff, const float* __restrict__ raw,
                        float* __restrict__ out, int T) {
    __shared__ float ls[256 + KLEN - 1];
    __shared__ float ker[KLEN];
    int tid = threadIdx.x;
    int base = blockIdx.x * 256;
    if (tid < 64) {  // wave 0 computes the 64-tap softmax gamma kernel
        float delay = physp(raw, 21, 0.01f, 5.0f);  // mu_t
        float theta = fmaxf(delay, 1e-3f) * (1.0f / 2.5f);
        float tt = (float)tid + 0.5f;
        float logk = 1.5f * __logf(tt) - tt / theta;
        float m = logk;
#pragma unroll
        for (int o = 32; o >= 1; o >>= 1) m = fmaxf(m, __shfl_xor(m, o, 64));
        float e = __expf(logk - m);
        float s = e;
#pragma unroll
        for (int o = 32; o >= 1; o >>= 1) s += __shfl_xor(s, o, 64);
        ker[tid] = e / s;
    }
    for (int i = tid; i < 256 + KLEN - 1; i += 256) {
        int t = base - (KLEN - 1) + i;
        ls[i] = (t >= 0 && t < T) ? runoff[t] : 0.0f;
    }
    __syncthreads();
    float acc = 0.0f;
#pragma unroll
    for (int k = 0; k < KLEN; ++k) acc += ker[k] * ls[tid + (KLEN - 1) - k];
    int t = base + tid;
    if (t < T) out[t] = acc;
}

extern "C" void kernel_launch(void* const* d_in, const int* in_sizes, int n_in,
                              void* d_out, int out_size, void* d_ws, size_t ws_size,
                              hipStream_t stream) {
    const float* forcing = (const float*)d_in[0];  // [T,3]
    const float* raw = (const float*)d_in[1];      // [29]
    float* out = (float*)d_out;
    float* ws = (float*)d_ws;

    int T = in_sizes[0] / 3;
    int nchunk = (T + CHUNK_L - 1) / CHUNK_L;
    int P = ((nchunk + 7) / 8) * 8;  // keep 16B alignment of each region

    float* s1s = ws;
    float* q12s = ws + P;
    float* s2s = ws + 2 * P;
    float* runoff = ws + 3 * P;

    k_s1<<<(nchunk + 255) / 256, 256, 0, stream>>>(forcing, raw, s1s, q12s, T, nchunk);
    k_s2coarse<<<1, 64, 0, stream>>>(raw, q12s, s2s, nchunk);
    k_sim<<<(nchunk + 255) / 256, 256, 0, stream>>>(forcing, raw, s1s, s2s, runoff, T, nchunk);
    k_route<<<(T + 255) / 256, 256, 0, stream>>>(runoff, raw, out, T);
}

// Round 4
// 73.386 us; speedup vs baseline: 3.5339x; 1.8652x over previous
//
#include <hip/hip_runtime.h>

#define KLEN 64
#define FCH 16            // fine chunk length (steps)
#define WARMUP 64         // S1 contraction ~0.8/step -> 0.8^64 ~ 6e-7 rel
#define WIN_FC 64         // fine chunks per S2 window (= 1024 steps, one wave)
#define S1_INIT_V 50.0f
#define S2_INIT_V 250.0f

__device__ __forceinline__ float fpow(float x, float e) {
    // x >= 0; x==0 -> log2=-inf -> exp2=0 (exponents here are > 0)
    return exp2f(e * __log2f(x));
}
__device__ __forceinline__ float clamp01(float x) { return fminf(fmaxf(x, 0.0f), 1.0f); }
__device__ __forceinline__ float physp(const float* raw, int i, float lo, float hi) {
    return lo + (hi - lo) / (1.0f + __expf(-raw[i]));
}

// ---- 8-step forcing group: 24 floats = 6 float4 (16B-aligned when t%8==0) ----
struct F8 { float4 v[6]; };
__device__ __forceinline__ F8 load_f8(const float* __restrict__ forc, int t) {
    const float4* p = (const float4*)(forc + 3 * t);
    F8 r;
#pragma unroll
    for (int k = 0; k < 6; ++k) r.v[k] = p[k];
    return r;
}
__device__ __forceinline__ float f4c(const float4& v, int c) {
    return c == 0 ? v.x : c == 1 ? v.y : c == 2 ? v.z : v.w;
}
__device__ __forceinline__ float f8_get(const F8& f, int i) { return f4c(f.v[i >> 2], i & 3); }

// S1-only step; shares one log2 between the two powers
#define S1_CORE(pr, pe, te, QACC)                                         \
    {                                                                     \
        float rain = (te) > Train ? (pr) : 0.0f;                          \
        float s1f = clamp01(S1 * invS1);                                  \
        float lg = __log2f(s1f);                                          \
        float e1 = (pe)*fminf(s1f * invft, 1.0f);                         \
        float qsx = rain * exp2f(b * lg);                                 \
        float q12 = ku * exp2f(cc * lg);                                  \
        float qif = ki * s1f;                                             \
        S1 = fminf(fmaxf(S1 + rain - qsx - e1 - q12 - qif, 0.0f), S1max); \
        QACC;                                                             \
    }

// ---- Phase A: per-fine-chunk S1 spin-up; outputs S1 start, q12 fine-sum, window inflow ----
__global__ void __launch_bounds__(64) k_s1(
        const float* __restrict__ forc, const float* __restrict__ raw,
        float* __restrict__ s1s, float* __restrict__ q12f, float* __restrict__ Qw,
        int T, int nfine) {
    int lane = threadIdx.x;
    int j = blockIdx.x * WIN_FC + lane;
    bool active = j < nfine;

    const float S1max  = physp(raw, 0, 50.0f, 5000.0f);
    const float f_tens = physp(raw, 2, 0.05f, 0.95f);
    const float ku     = physp(raw, 6, 0.01f, 1000.0f);
    const float cc     = physp(raw, 7, 1.0f, 20.0f);
    const float ki     = physp(raw, 11, 0.01f, 1000.0f);
    const float b      = physp(raw, 18, 0.001f, 3.0f);
    const float Train  = physp(raw, 22, -2.0f, 4.0f);
    const float invS1 = 1.0f / S1max, invft = 1.0f / f_tens;

    float S1 = S1_INIT_V;
    float Q = 0.0f;
    if (active) {
        int t0 = j * FCH;
        int tend = min(t0 + FCH, T);
        int ts = max(t0 - WARMUP, 0);

        int ngw = (t0 - ts) >> 3;  // multiples of 8 by construction
        F8 cur = load_f8(forc, ts);
        for (int g = 0; g < ngw; ++g) {
            F8 nxt = load_f8(forc, ts + 8 * (g + 1));  // last prefetch = first main group
#pragma unroll
            for (int s = 0; s < 8; ++s) {
                float pr = f8_get(cur, 3 * s), pe = f8_get(cur, 3 * s + 1), te = f8_get(cur, 3 * s + 2);
                S1_CORE(pr, pe, te, );
            }
            cur = nxt;
        }
        s1s[j] = S1;

        int ngm = (tend - t0) >> 3;
        for (int g = 0; g < ngm; ++g) {
            F8 nxt = load_f8(forc, t0 + 8 * min(g + 1, ngm - 1));
#pragma unroll
            for (int s = 0; s < 8; ++s) {
                float pr = f8_get(cur, 3 * s), pe = f8_get(cur, 3 * s + 1), te = f8_get(cur, 3 * s + 2);
                S1_CORE(pr, pe, te, Q += q12);
            }
            cur = nxt;
        }
        for (int t = t0 + 8 * ngm; t < tend; ++t) {  // generic tail
            float pr = forc[3 * t], pe = forc[3 * t + 1], te = forc[3 * t + 2];
            S1_CORE(pr, pe, te, Q += q12);
        }
        q12f[j] = Q;
    }
    // wave-reduce Q -> window inflow
    float s = Q;
#pragma unroll
    for (int o = 32; o >= 1; o >>= 1) s += __shfl_xor(s, o, 64);
    if (lane == 0) Qw[blockIdx.x] = s;
}

// ---- Phase B: Picard fixed-point for window-start S2 (1 wave; fallback sequential) ----
__global__ void __launch_bounds__(64) k_s2win(
        const float* __restrict__ raw, const float* __restrict__ Qw,
        const float* __restrict__ q12f,
        float* __restrict__ S2win, float* __restrict__ qbwin,
        float* __restrict__ s2fine, int* __restrict__ flag,
        int T, int nfine) {
    int lane = threadIdx.x;
    const float S2max = physp(raw, 1, 100.0f, 10000.0f);
    const float ks    = physp(raw, 12, 0.001f, 10000.0f);
    const float nn    = physp(raw, 13, 1.0f, 10.0f);
    const float invS2 = 1.0f / S2max;

    int NW = (nfine + WIN_FC - 1) / WIN_FC;
    int WSTEPS = WIN_FC * FCH;  // 1024

    int w0 = 2 * lane, w1 = 2 * lane + 1;
    float L0 = (w0 < NW) ? (float)min(WSTEPS, T - WSTEPS * w0) : 0.0f;
    float L1 = (w1 < NW) ? (float)min(WSTEPS, T - WSTEPS * w1) : 0.0f;
    float Q0 = (w0 < NW) ? Qw[w0] : 0.0f;
    float Q1 = (w1 < NW) ? Qw[w1] : 0.0f;

    float qb0 = ks * fpow(clamp01(S2_INIT_V * invS2), nn);
    float qb1 = qb0;
    float S20 = S2_INIT_V, S21 = S2_INIT_V;
    bool picard_ok = (NW <= 128);
    if (picard_ok) {
        for (int it = 0; it < 12; ++it) {
            float d0 = Q0 - L0 * qb0;
            float d1 = Q1 - L1 * qb1;
            float pair = d0 + d1;
            float sc = pair;  // inclusive lane scan
#pragma unroll
            for (int o = 1; o < 64; o <<= 1) {
                float v = __shfl_up(sc, o, 64);
                if (lane >= o) sc += v;
            }
            float excl = sc - pair;
            S20 = S2_INIT_V + excl;
            S21 = S20 + d0;
            qb0 = ks * fpow(clamp01(S20 * invS2), nn);
            qb1 = ks * fpow(clamp01(S21 * invS2), nn);
        }
        // bounds check: window trajectories must stay well inside [0, S2max]
        bool bad = false;
        if (w0 < NW) bad |= (S20 - L0 * qb0 < 0.5f) || (S20 + Q0 > S2max - 0.5f);
        if (w1 < NW) bad |= (S21 - L1 * qb1 < 0.5f) || (S21 + Q1 > S2max - 0.5f);
        picard_ok = (__ballot(bad) == 0ULL);
    }
    if (picard_ok) {
        if (w0 < NW) { S2win[w0] = S20; qbwin[w0] = qb0; }
        if (w1 < NW) { S2win[w1] = S21; qbwin[w1] = qb1; }
        if (lane == 0) *flag = 0;
    } else if (lane == 0) {
        // exact-ish sequential fallback (clamped, qb frozen per window)
        *flag = 1;
        float S2 = S2_INIT_V;
        for (int w = 0; w < NW; ++w) {
            float s2f = clamp01(S2 * invS2);
            float qb = ks * fpow(s2f, nn);
            S2win[w] = S2; qbwin[w] = qb;
            int i0 = w * WIN_FC, i1 = min(i0 + WIN_FC, nfine);
            for (int i = i0; i < i1; ++i) {
                s2fine[i] = S2;
                float steps = (float)min(FCH, T - FCH * i);
                S2 = fminf(fmaxf(S2 + q12f[i] - steps * qb, 0.0f), S2max);
            }
        }
    }
}

// ---- Phase C: exact per-fine-chunk re-simulation; S2 start reconstructed in-wave ----
__global__ void __launch_bounds__(64) k_sim(
        const float* __restrict__ forc, const float* __restrict__ raw,
        const float* __restrict__ s1s, const float* __restrict__ q12f,
        const float* __restrict__ S2win, const float* __restrict__ qbwin,
        const float* __restrict__ s2fine, const int* __restrict__ flag,
        float* __restrict__ runoff, int T, int nfine) {
    int lane = threadIdx.x;
    int j = blockIdx.x * WIN_FC + lane;
    bool active = j < nfine;

    const float S1max  = physp(raw, 0, 50.0f, 5000.0f);
    const float S2max  = physp(raw, 1, 100.0f, 10000.0f);
    const float f_tens = physp(raw, 2, 0.05f, 0.95f);
    const float ku     = physp(raw, 6, 0.01f, 1000.0f);
    const float ki     = physp(raw, 11, 0.01f, 1000.0f);
    const float ks     = physp(raw, 12, 0.001f, 10000.0f);
    const float nn     = physp(raw, 13, 1.0f, 10.0f);
    const float cc     = physp(raw, 7, 1.0f, 20.0f);
    const float b      = physp(raw, 18, 0.001f, 3.0f);
    const float Train  = physp(raw, 22, -2.0f, 4.0f);
    const float invS1 = 1.0f / S1max, invS2 = 1.0f / S2max, invft = 1.0f / f_tens;

    float q = active ? q12f[j] : 0.0f;
    float S2;
    if (*flag) {
        S2 = active ? s2fine[j] : 0.0f;
    } else {
        float sc = q;  // wave exclusive prefix of window-local q12
#pragma unroll
        for (int o = 1; o < 64; o <<= 1) {
            float v = __shfl_up(sc, o, 64);
            if (lane >= o) sc += v;
        }
        float excl = sc - q;
        S2 = S2win[blockIdx.x] + excl - qbwin[blockIdx.x] * (float)(FCH * lane);
        S2 = fminf(fmaxf(S2, 0.0f), S2max);
    }
    if (!active) return;

    float S1 = s1s[j];
    int t0 = j * FCH;
    int tend = min(t0 + FCH, T);

#define SIM_CORE(pr, pe, te, EMIT)                                        \
    {                                                                     \
        float rain = (te) > Train ? (pr) : 0.0f;                          \
        float s1f = clamp01(S1 * invS1);                                  \
        float s2f = clamp01(S2 * invS2);                                  \
        float lg = __log2f(s1f);                                          \
        float e1 = (pe)*fminf(s1f * invft, 1.0f);                         \
        float qsx = rain * exp2f(b * lg);                                 \
        float q12 = ku * exp2f(cc * lg);                                  \
        float qif = ki * s1f;                                             \
        float qb = ks * fpow(s2f, nn);                                    \
        EMIT;                                                             \
        S1 = fminf(fmaxf(S1 + rain - qsx - e1 - q12 - qif, 0.0f), S1max); \
        S2 = fminf(fmaxf(S2 + q12 - qb, 0.0f), S2max);                    \
    }

    int ngm = (tend - t0) >> 3;
    if (ngm > 0) {
        F8 cur = load_f8(forc, t0);
        for (int g = 0; g < ngm; ++g) {
            F8 nxt = load_f8(forc, t0 + 8 * min(g + 1, ngm - 1));
            float ro[8];
#pragma unroll
            for (int s = 0; s < 8; ++s) {
                float pr = f8_get(cur, 3 * s), pe = f8_get(cur, 3 * s + 1), te = f8_get(cur, 3 * s + 2);
                SIM_CORE(pr, pe, te, ro[s] = qsx + qif + qb);
            }
            float4* rp = (float4*)(runoff + t0 + 8 * g);
            rp[0] = make_float4(ro[0], ro[1], ro[2], ro[3]);
            rp[1] = make_float4(ro[4], ro[5], ro[6], ro[7]);
            cur = nxt;
        }
    }
    for (int t = t0 + 8 * ngm; t < tend; ++t) {  // generic tail
        float pr = forc[3 * t], pe = forc[3 * t + 1], te = forc[3 * t + 2];
        SIM_CORE(pr, pe, te, runoff[t] = qsx + qif + qb);
    }
}

// ---- Phase D: causal gamma-kernel routing conv (self-computes weights) ----
__global__ void k_route(const float* __restrict__ runoff, const float* __restrict__ raw,
                        float* __restrict__ out, int T) {
    __shared__ float ls[256 + KLEN - 1];
    __shared__ float ker[KLEN];
    int tid = threadIdx.x;
    int base = blockIdx.x * 256;
    if (tid < 64) {  // wave 0 computes the 64-tap softmax gamma kernel
        float delay = physp(raw, 21, 0.01f, 5.0f);  // mu_t
        float theta = fmaxf(delay, 1e-3f) * (1.0f / 2.5f);
        float tt = (float)tid + 0.5f;
        float logk = 1.5f * __logf(tt) - tt / theta;
        float m = logk;
#pragma unroll
        for (int o = 32; o >= 1; o >>= 1) m = fmaxf(m, __shfl_xor(m, o, 64));
        float e = __expf(logk - m);
        float s = e;
#pragma unroll
        for (int o = 32; o >= 1; o >>= 1) s += __shfl_xor(s, o, 64);
        ker[tid] = e / s;
    }
    for (int i = tid; i < 256 + KLEN - 1; i += 256) {
        int t = base - (KLEN - 1) + i;
        ls[i] = (t >= 0 && t < T) ? runoff[t] : 0.0f;
    }
    __syncthreads();
    float acc = 0.0f;
#pragma unroll
    for (int k = 0; k < KLEN; ++k) acc += ker[k] * ls[tid + (KLEN - 1) - k];
    int t = base + tid;
    if (t < T) out[t] = acc;
}

extern "C" void kernel_launch(void* const* d_in, const int* in_sizes, int n_in,
                              void* d_out, int out_size, void* d_ws, size_t ws_size,
                              hipStream_t stream) {
    const float* forcing = (const float*)d_in[0];  // [T,3]
    const float* raw = (const float*)d_in[1];      // [29]
    float* out = (float*)d_out;
    float* ws = (float*)d_ws;

    int T = in_sizes[0] / 3;
    int nfine = (T + FCH - 1) / FCH;
    int NW = (nfine + WIN_FC - 1) / WIN_FC;
    int P = ((nfine + 7) / 8) * 8;
    int PW = ((NW + 7) / 8) * 8;

    float* s1s = ws;             // [P]
    float* q12f = s1s + P;       // [P]
    float* Qw = q12f + P;        // [PW]
    float* S2win = Qw + PW;      // [PW]
    float* qbwin = S2win + PW;   // [PW]
    float* s2fine = qbwin + PW;  // [P]
    int* flag = (int*)(s2fine + P);  // [8]
    float* runoff = (float*)(flag + 8);  // [T]

    k_s1<<<NW, 64, 0, stream>>>(forcing, raw, s1s, q12f, Qw, T, nfine);
    k_s2win<<<1, 64, 0, stream>>>(raw, Qw, q12f, S2win, qbwin, s2fine, flag, T, nfine);
    k_sim<<<NW, 64, 0, stream>>>(forcing, raw, s1s, q12f, S2win, qbwin, s2fine, flag,
                                 runoff, T, nfine);
    k_route<<<(T + 255) / 256, 256, 0, stream>>>(runoff, raw, out, T);
}